// Round 1
// baseline (1348.826 us; speedup 1.0000x reference)
//
#include <hip/hip_runtime.h>
#include <hip/hip_bf16.h>

typedef unsigned short u16;
typedef float f32x4 __attribute__((ext_vector_type(4)));
typedef short s16x8 __attribute__((ext_vector_type(8)));

#define L 2048
#define H 3072
#define NH 24
#define D 128
#define NQK 9216
#define N1 21504
#define CATN 15360

__device__ __forceinline__ u16 f2bf(float f){
  union { float f; unsigned int u; } x; x.f = f;
  unsigned int r = x.u + 0x7fffu + ((x.u >> 16) & 1u);
  return (u16)(r >> 16);
}
__device__ __forceinline__ float bf2f(u16 u){
  union { unsigned int u; float f; } x; x.u = ((unsigned int)u) << 16; return x.f;
}
__device__ __forceinline__ void gload_lds(const u16* g, u16* l){
  __builtin_amdgcn_global_load_lds((const __attribute__((address_space(1))) void*)g,
                                   (__attribute__((address_space(3))) void*)l, 16, 0, 0);
}

// ---------------- modulation GEMV: part[kc][col] = sum_k silu(vec[k]) * mod_w[k][col]
__global__ __launch_bounds__(256) void k_mod(const float* __restrict__ vec,
                                             const float* __restrict__ mw,
                                             float* __restrict__ part){
  __shared__ float sv[128];
  int col = blockIdx.x*256 + threadIdx.x;
  int kc  = blockIdx.y;
  if (threadIdx.x < 128){
    float v = vec[kc*128 + threadIdx.x];
    sv[threadIdx.x] = v / (1.f + __expf(-v));
  }
  __syncthreads();
  float acc = 0.f;
  const float* wp = mw + (size_t)(kc*128)*NQK + col;
  #pragma unroll 8
  for (int k=0;k<128;++k) acc += sv[k]*wp[(size_t)k*NQK];
  part[kc*NQK + col] = acc;
}

__global__ __launch_bounds__(256) void k_modred(const float* __restrict__ part,
                                                const float* __restrict__ mod_b,
                                                float* __restrict__ mod){
  int col = blockIdx.x*256 + threadIdx.x;
  float s = mod_b[col];
  #pragma unroll
  for (int j=0;j<24;++j) s += part[j*NQK + col];
  mod[col] = s;
}

// ---------------- LayerNorm + (1+scale)*xn + shift -> bf16
__global__ __launch_bounds__(256) void k_ln(const float* __restrict__ x,
                                            const float* __restrict__ mod,
                                            const float* __restrict__ lns,
                                            const float* __restrict__ lnb,
                                            u16* __restrict__ xmod){
  int row = blockIdx.x, tid = threadIdx.x;
  const float4* xr = (const float4*)(x + (size_t)row*H);
  float4 v[3];
  float s=0.f, ss=0.f;
  #pragma unroll
  for (int i=0;i<3;++i){
    v[i] = xr[tid + i*256];
    s  += v[i].x+v[i].y+v[i].z+v[i].w;
    ss += v[i].x*v[i].x + v[i].y*v[i].y + v[i].z*v[i].z + v[i].w*v[i].w;
  }
  #pragma unroll
  for (int off=1; off<64; off<<=1){ s += __shfl_xor(s,off); ss += __shfl_xor(ss,off); }
  __shared__ float red[8];
  int lane = tid&63, wid = tid>>6;
  if (!lane){ red[wid]=s; red[4+wid]=ss; }
  __syncthreads();
  s  = red[0]+red[1]+red[2]+red[3];
  ss = red[4]+red[5]+red[6]+red[7];
  float mu = s*(1.f/H);
  float var = ss*(1.f/H) - mu*mu;
  float rr = rsqrtf(var + 1e-6f);
  u16* op = xmod + (size_t)row*H;
  #pragma unroll
  for (int i=0;i<3;++i){
    int c0 = (tid + i*256)*4;
    float e[4] = {v[i].x, v[i].y, v[i].z, v[i].w};
    #pragma unroll
    for (int j=0;j<4;++j){
      int c = c0+j;
      float xn = (e[j]-mu)*rr*lns[c] + lnb[c];
      float xm = (1.f + mod[H+c])*xn + mod[c];
      op[c] = f2bf(xm);
    }
  }
}

// ---------------- transpose + f32->bf16: in[R][C] -> out[C][R]
__global__ __launch_bounds__(256) void k_tcvt(const float* __restrict__ in,
                                              u16* __restrict__ out, int R, int C){
  __shared__ u16 t[64][65];
  int c0 = blockIdx.x*64, r0 = blockIdx.y*64;
  int tx = threadIdx.x & 63, ty = threadIdx.x >> 6;
  #pragma unroll
  for (int i=0;i<64;i+=4){
    int r = i+ty;
    t[tx][r] = f2bf(in[(size_t)(r0+r)*C + c0 + tx]);
  }
  __syncthreads();
  #pragma unroll
  for (int i=0;i<64;i+=4){
    int c = i+ty;
    out[(size_t)(c0+c)*R + r0 + tx] = t[c][tx];
  }
}

// ---------------- bf16 transpose for V: in[24][L][D] -> out[24][D][L]
__global__ __launch_bounds__(256) void k_tv(const u16* __restrict__ in,
                                            u16* __restrict__ out){
  __shared__ u16 t[64][65];
  int h = blockIdx.z;
  int d0 = blockIdx.x*64, l0 = blockIdx.y*64;
  const u16* ib = in  + (size_t)h*L*D;
  u16*       ob = out + (size_t)h*D*L;
  int tx = threadIdx.x & 63, ty = threadIdx.x >> 6;
  #pragma unroll
  for (int i=0;i<64;i+=4){
    int l = i+ty;
    t[tx][l] = ib[(size_t)(l0+l)*D + d0 + tx];
  }
  __syncthreads();
  #pragma unroll
  for (int i=0;i<64;i+=4){
    int d = i+ty;
    ob[(size_t)(d0+d)*L + l0 + tx] = t[d][tx];
  }
}

// ---------------- q/k rmsnorm + scale + rope (in place, bf16)
__global__ __launch_bounds__(256) void k_rope(u16* __restrict__ qkv,
                                              const float* __restrict__ qs,
                                              const float* __restrict__ ks,
                                              const float* __restrict__ pe){
  int w = blockIdx.x*4 + (threadIdx.x>>6);
  int lane = threadIdx.x & 63;
  int which = w / (NH*L);
  int rem   = w - which*(NH*L);
  int head  = rem >> 11;
  int l     = rem & 2047;
  const float* sc = which ? ks : qs;
  u16* p = qkv + ((size_t)(which*NH + head)*L + l)*D + lane*2;
  float t0 = bf2f(p[0]), t1 = bf2f(p[1]);
  float ssum = t0*t0 + t1*t1;
  #pragma unroll
  for (int off=1; off<64; off<<=1) ssum += __shfl_xor(ssum, off);
  float rr = rsqrtf(ssum*(1.f/128.f) + 1e-6f);
  t0 *= rr*sc[lane*2];
  t1 *= rr*sc[lane*2+1];
  float4 r4 = ((const float4*)pe)[(size_t)l*64 + lane];
  float o0 = r4.x*t0 + r4.y*t1;
  float o1 = r4.z*t0 + r4.w*t1;
  p[0] = f2bf(o0); p[1] = f2bf(o1);
}

// ---------------- GEMM: A[M][K] bf16 row-major, B[N][K] bf16 (= B^T), 128x128 tile, BK=64
// EPI 0: h-split epilogue (qkv scatter + gelu->cat).  EPI 1: out = x + gate*(acc+bias)
template<int EPI>
__global__ __launch_bounds__(256, 2) void k_gemm(const u16* __restrict__ A,
                                                 const u16* __restrict__ B, int K,
                                                 const float* __restrict__ bias,
                                                 u16* __restrict__ qkv, u16* __restrict__ cat,
                                                 const float* __restrict__ xres,
                                                 const float* __restrict__ mod,
                                                 float* __restrict__ outf){
  __shared__ __align__(16) u16 As[8192];
  __shared__ __align__(16) u16 Bs[8192];
  const int m0 = blockIdx.x*128, n0 = blockIdx.y*128;
  const int tid = threadIdx.x, lane = tid & 63, wid = tid >> 6;
  const int wr = wid >> 1, wc = wid & 1, l15 = lane & 15, hi = lane >> 4;

  const u16* pA[4]; const u16* pB[4];
  #pragma unroll
  for (int i=0;i<4;++i){
    int b = (wid*4+i)*1024 + lane*16;
    int row = b >> 7;
    int obo = (b & 127) ^ ((row & 7) << 4);
    pA[i] = A + (size_t)(m0+row)*K + (obo>>1);
    pB[i] = B + (size_t)(n0+row)*K + (obo>>1);
  }
  f32x4 acc[4][4] = {};
  const int nk = K >> 6;
  for (int kt=0; kt<nk; ++kt){
    #pragma unroll
    for (int i=0;i<4;++i){
      gload_lds(pA[i], &As[(wid*4+i)*512]);
      gload_lds(pB[i], &Bs[(wid*4+i)*512]);
      pA[i] += 64; pB[i] += 64;
    }
    __syncthreads();
    #pragma unroll
    for (int ks=0; ks<2; ++ks){
      s16x8 af[4], bf[4];
      #pragma unroll
      for (int mi=0; mi<4; ++mi){
        int row = wr*64 + mi*16 + l15;
        int byt = (row<<7) + ks*64 + hi*16; byt ^= (row&7)<<4;
        af[mi] = *(const s16x8*)((const char*)As + byt);
      }
      #pragma unroll
      for (int ni=0; ni<4; ++ni){
        int row = wc*64 + ni*16 + l15;
        int byt = (row<<7) + ks*64 + hi*16; byt ^= (row&7)<<4;
        bf[ni] = *(const s16x8*)((const char*)Bs + byt);
      }
      #pragma unroll
      for (int mi=0; mi<4; ++mi)
        #pragma unroll
        for (int ni=0; ni<4; ++ni)
          acc[mi][ni] = __builtin_amdgcn_mfma_f32_16x16x32_bf16(af[mi], bf[ni], acc[mi][ni], 0,0,0);
    }
    __syncthreads();
  }
  #pragma unroll
  for (int mi=0; mi<4; ++mi){
    #pragma unroll
    for (int ni=0; ni<4; ++ni){
      int col = n0 + wc*64 + ni*16 + l15;
      #pragma unroll
      for (int r=0; r<4; ++r){
        int row = m0 + wr*64 + mi*16 + hi*4 + r;
        float v = acc[mi][ni][r] + bias[col];
        if (EPI == 0){
          if (col < NQK){
            int which = col / H;
            int rem = col - which*H;
            int head = rem >> 7, d = rem & 127;
            qkv[((size_t)(which*NH + head)*L + row)*D + d] = f2bf(v);
          } else {
            float g = 0.5f*v*(1.f + tanhf(0.7978845608028654f*(v + 0.044715f*v*v*v)));
            cat[(size_t)row*CATN + (H + col - NQK)] = f2bf(g);
          }
        } else {
          size_t idx = (size_t)row*H + col;
          outf[idx] = xres[idx] + mod[2*H + col]*v;
        }
      }
    }
  }
}

// ---------------- flash attention: 1 head x 64 q-rows per block, 4 waves x 16 rows
__global__ __launch_bounds__(256, 2) void k_attn(const u16* __restrict__ qkv,
                                                 const u16* __restrict__ vt,
                                                 u16* __restrict__ cat){
  __shared__ __align__(16) u16 Ks_[8192];   // [kv 64][d 128] swizzled
  __shared__ __align__(16) u16 Vs_[8192];   // [d 128][kv 64] swizzled
  __shared__ __align__(16) u16 Ps[4][1024]; // per-wave [16][64] swizzled
  const int head = blockIdx.x, qt = blockIdx.y;
  const int tid = threadIdx.x, lane = tid&63, wid = tid>>6;
  const int l15 = lane&15, hi = lane>>4;
  const u16* qb = qkv + (size_t)head*L*D;
  const u16* kb = qkv + (size_t)(NH+head)*L*D;
  const u16* vb = vt  + (size_t)head*D*L;
  const int q0 = qt*64 + wid*16;
  s16x8 qf[4];
  #pragma unroll
  for (int ksx=0;ksx<4;++ksx)
    qf[ksx] = *(const s16x8*)(qb + (size_t)(q0+l15)*D + ksx*32 + hi*8);
  f32x4 o[8] = {};
  float m_[4], ls[4];
  #pragma unroll
  for (int r=0;r<4;++r){ m_[r] = -1e30f; ls[r] = 0.f; }

  const u16* pK[4]; const u16* pV[4];
  u16* dK[4]; u16* dV[4];
  #pragma unroll
  for (int i=0;i<4;++i){
    int b = (wid*4+i)*1024 + lane*16;
    { int row = b >> 8; int obo = (b&255) ^ ((row&7)<<4);
      pK[i] = kb + (size_t)row*D + (obo>>1); dK[i] = &Ks_[(wid*4+i)*512]; }
    { int row = b >> 7; int obo = (b&127) ^ ((row&7)<<4);
      pV[i] = vb + (size_t)row*L + (obo>>1); dV[i] = &Vs_[(wid*4+i)*512]; }
  }
  const float SC = 0.08838834764831845f;
  for (int t=0; t<L/64; ++t){
    #pragma unroll
    for (int i=0;i<4;++i){
      gload_lds(pK[i], dK[i]);
      gload_lds(pV[i], dV[i]);
      pK[i] += 64*D; pV[i] += 64;
    }
    __syncthreads();
    f32x4 s[4] = {};
    #pragma unroll
    for (int ksx=0;ksx<4;++ksx){
      s16x8 kf[4];
      #pragma unroll
      for (int nf=0;nf<4;++nf){
        int row = nf*16 + l15;
        int byt = (row<<8) + ksx*64 + hi*16; byt ^= (row&7)<<4;
        kf[nf] = *(const s16x8*)((const char*)Ks_ + byt);
      }
      #pragma unroll
      for (int nf=0;nf<4;++nf)
        s[nf] = __builtin_amdgcn_mfma_f32_16x16x32_bf16(qf[ksx], kf[nf], s[nf], 0,0,0);
    }
    float mt[4], al[4], rs[4];
    #pragma unroll
    for (int r=0;r<4;++r){
      float a = fmaxf(fmaxf(s[0][r], s[1][r]), fmaxf(s[2][r], s[3][r]));
      a = fmaxf(a, __shfl_xor(a,1)); a = fmaxf(a, __shfl_xor(a,2));
      a = fmaxf(a, __shfl_xor(a,4)); a = fmaxf(a, __shfl_xor(a,8));
      mt[r] = a*SC;
    }
    #pragma unroll
    for (int r=0;r<4;++r){
      float mn = fmaxf(m_[r], mt[r]);
      al[r] = __expf(m_[r] - mn);
      m_[r] = mn; rs[r] = 0.f;
    }
    #pragma unroll
    for (int nf=0;nf<4;++nf)
      #pragma unroll
      for (int r=0;r<4;++r){
        float p = __expf(s[nf][r]*SC - m_[r]);
        s[nf][r] = p; rs[r] += p;
      }
    #pragma unroll
    for (int r=0;r<4;++r){
      float a = rs[r];
      a += __shfl_xor(a,1); a += __shfl_xor(a,2);
      a += __shfl_xor(a,4); a += __shfl_xor(a,8);
      ls[r] = ls[r]*al[r] + a;
    }
    #pragma unroll
    for (int nfd=0;nfd<8;++nfd)
      #pragma unroll
      for (int r=0;r<4;++r) o[nfd][r] *= al[r];
    #pragma unroll
    for (int nf=0;nf<4;++nf)
      #pragma unroll
      for (int r=0;r<4;++r){
        int prow = hi*4 + r;
        int byt = (prow<<7) + (nf*16+l15)*2; byt ^= (prow&7)<<4;
        *(u16*)((char*)Ps[wid] + byt) = f2bf(s[nf][r]);
      }
    #pragma unroll
    for (int k2=0;k2<2;++k2){
      int pbyt = (l15<<7) + k2*64 + hi*16; pbyt ^= (l15&7)<<4;
      s16x8 pf = *(const s16x8*)((const char*)Ps[wid] + pbyt);
      #pragma unroll
      for (int nfd=0;nfd<8;++nfd){
        int row = nfd*16 + l15;
        int byt = (row<<7) + k2*64 + hi*16; byt ^= (row&7)<<4;
        s16x8 vf = *(const s16x8*)((const char*)Vs_ + byt);
        o[nfd] = __builtin_amdgcn_mfma_f32_16x16x32_bf16(pf, vf, o[nfd], 0,0,0);
      }
    }
    __syncthreads();
  }
  #pragma unroll
  for (int r=0;r<4;++r){
    float inv = 1.f/ls[r];
    int qrow = qt*64 + wid*16 + hi*4 + r;
    #pragma unroll
    for (int nfd=0;nfd<8;++nfd){
      int d = nfd*16 + l15;
      cat[(size_t)qrow*CATN + head*D + d] = f2bf(o[nfd][r]*inv);
    }
  }
}

extern "C" void kernel_launch(void* const* d_in, const int* in_sizes, int n_in,
                              void* d_out, int out_size, void* d_ws, size_t ws_size,
                              hipStream_t stream){
  const float* x     = (const float*)d_in[0];
  const float* vec   = (const float*)d_in[1];
  const float* pe    = (const float*)d_in[2];
  const float* mod_w = (const float*)d_in[3];
  const float* mod_b = (const float*)d_in[4];
  const float* ln_s  = (const float*)d_in[5];
  const float* ln_b  = (const float*)d_in[6];
  const float* w1    = (const float*)d_in[7];
  const float* b1    = (const float*)d_in[8];
  const float* q_s   = (const float*)d_in[9];
  const float* k_s   = (const float*)d_in[10];
  const float* w2    = (const float*)d_in[11];
  const float* b2    = (const float*)d_in[12];
  float* out = (float*)d_out;

  char* ws = (char*)d_ws;
  size_t off = 0;
  float* part = (float*)(ws + off); off += (size_t)24*NQK*4;
  float* mod  = (float*)(ws + off); off += (size_t)NQK*4;
  u16* xmod = (u16*)(ws + off); off += (size_t)L*H*2;
  u16* qkv  = (u16*)(ws + off); off += (size_t)3*NH*L*D*2;
  u16* vtb  = (u16*)(ws + off); off += (size_t)NH*D*L*2;
  u16* cat  = (u16*)(ws + off); off += (size_t)L*CATN*2;
  u16* wbuf = (u16*)(ws + off); off += (size_t)N1*H*2;   // reused: w1t then w2t

  hipLaunchKernelGGL(k_mod, dim3(36,24), dim3(256), 0, stream, vec, mod_w, part);
  hipLaunchKernelGGL(k_modred, dim3(36), dim3(256), 0, stream, part, mod_b, mod);
  hipLaunchKernelGGL(k_ln, dim3(2048), dim3(256), 0, stream, x, mod, ln_s, ln_b, xmod);
  hipLaunchKernelGGL(k_tcvt, dim3(N1/64, H/64), dim3(256), 0, stream, w1, wbuf, H, N1);
  hipLaunchKernelGGL((k_gemm<0>), dim3(16,168), dim3(256), 0, stream,
                     xmod, wbuf, H, b1, qkv, cat,
                     (const float*)nullptr, (const float*)nullptr, (float*)nullptr);
  hipLaunchKernelGGL(k_rope, dim3(2*NH*L/4), dim3(256), 0, stream, qkv, q_s, k_s, pe);
  hipLaunchKernelGGL(k_tv, dim3(D/64, L/64, NH), dim3(256), 0, stream,
                     qkv + (size_t)2*NH*L*D, vtb);
  hipLaunchKernelGGL(k_attn, dim3(NH, L/64), dim3(256), 0, stream, qkv, vtb, cat);
  hipLaunchKernelGGL(k_tcvt, dim3(H/64, CATN/64), dim3(256), 0, stream, w2, wbuf, CATN, H);
  hipLaunchKernelGGL((k_gemm<1>), dim3(16,24), dim3(256), 0, stream,
                     cat, wbuf, CATN, b2,
                     (u16*)nullptr, (u16*)nullptr, x, mod, out);
}